// Round 9
// baseline (514.796 us; speedup 1.0000x reference)
//
#include <hip/hip_runtime.h>
#include <math.h>

#define N_NODES   100000
#define N_EDGES   1600000
#define N_FEAT    128
#define H_DIM     32
#define N_CLASSES 10
#define N_GRAPHS  64
#define NBLK      ((N_NODES + 255) / 256)   // 391

#define NS        8                          // dst slices (XCD-affine)
#define GPS       128                        // edge chunks per slice
#define NODES_PER_SLICE (N_NODES / NS)       // 12500
#define EDGES_PER_CHUNK (N_EDGES / GPS)      // 12500
#define CHUNK4    (EDGES_PER_CHUNK / 4)      // 3125 x 16B per chunk (12500%4==0)

typedef int v4i __attribute__((ext_vector_type(4)));  // clang vector: nt-load legal

// ---------------- CSR build ----------------
__global__ void zero_counts_kernel(int* __restrict__ counts) {
    int i = blockIdx.x * blockDim.x + threadIdx.x;
    if (i < N_NODES) counts[i] = 0;
}

// sliced histogram with non-temporal 16B edge loads: the 8x dst re-scan must
// not evict the XCD-local counts region from L2.
__global__ void hist_sliced_kernel(const int* __restrict__ dst, int* __restrict__ counts) {
    int slice = blockIdx.x & (NS - 1);
    int chunk = blockIdx.x >> 3;
    int lo_node = slice * NODES_PER_SLICE;
    const v4i* d4 = (const v4i*)(dst + chunk * EDGES_PER_CHUNK);
    for (int i = threadIdx.x; i < CHUNK4; i += 256) {
        v4i d = __builtin_nontemporal_load(&d4[i]);
        if ((unsigned)(d.x - lo_node) < (unsigned)NODES_PER_SLICE) atomicAdd(&counts[d.x], 1);
        if ((unsigned)(d.y - lo_node) < (unsigned)NODES_PER_SLICE) atomicAdd(&counts[d.y], 1);
        if ((unsigned)(d.z - lo_node) < (unsigned)NODES_PER_SLICE) atomicAdd(&counts[d.z], 1);
        if ((unsigned)(d.w - lo_node) < (unsigned)NODES_PER_SLICE) atomicAdd(&counts[d.w], 1);
    }
}

// per-block sums of counts
__global__ void scan_part1_kernel(const int* __restrict__ counts, int* __restrict__ bsums) {
    __shared__ int red[256];
    int t = threadIdx.x;
    int i = blockIdx.x * 256 + t;
    red[t] = (i < N_NODES) ? counts[i] : 0;
    __syncthreads();
    for (int off = 128; off > 0; off >>= 1) {
        if (t < off) red[t] += red[t + off];
        __syncthreads();
    }
    if (t == 0) bsums[blockIdx.x] = red[0];
}

// exclusive scan of bsums (NBLK <= 512), in place
__global__ void scan_part2_kernel(int* __restrict__ bsums) {
    __shared__ int s[512];
    int t = threadIdx.x;
    int v = (t < NBLK) ? bsums[t] : 0;
    s[t] = v;
    __syncthreads();
    for (int off = 1; off < 512; off <<= 1) {
        int x = (t >= off) ? s[t - off] : 0;
        __syncthreads();
        s[t] += x;
        __syncthreads();
    }
    if (t < NBLK) bsums[t] = s[t] - v;  // exclusive
}

// row_ptr = blockOff + excl-scan-in-block; cursor copy; dis = rsqrt(count+1)
__global__ void scan_part3_kernel(const int* __restrict__ counts, const int* __restrict__ bsums,
                                  int* __restrict__ row_ptr, int* __restrict__ cursor,
                                  float* __restrict__ dis) {
    __shared__ int s[256];
    int t = threadIdx.x;
    int i = blockIdx.x * 256 + t;
    int v = (i < N_NODES) ? counts[i] : 0;
    s[t] = v;
    __syncthreads();
    for (int off = 1; off < 256; off <<= 1) {
        int x = (t >= off) ? s[t - off] : 0;
        __syncthreads();
        s[t] += x;
        __syncthreads();
    }
    if (i < N_NODES) {
        int rp = bsums[blockIdx.x] + s[t] - v;
        row_ptr[i] = rp;
        cursor[i] = rp;
        dis[i] = rsqrtf((float)v + 1.0f);
        if (i == N_NODES - 1) row_ptr[N_NODES] = N_EDGES;
    }
}

// sliced fill, nt 16B edge loads: csr dirty lines (800KB/XCD) must survive in
// L2 until all 16 entries of each line are written -> write merging.
__global__ void fill_sliced_kernel(const int* __restrict__ src, const int* __restrict__ dst,
                                   int* __restrict__ cursor, int* __restrict__ csr) {
    int slice = blockIdx.x & (NS - 1);
    int chunk = blockIdx.x >> 3;
    int lo_node = slice * NODES_PER_SLICE;
    const v4i* d4 = (const v4i*)(dst + chunk * EDGES_PER_CHUNK);
    const v4i* s4 = (const v4i*)(src + chunk * EDGES_PER_CHUNK);
    for (int i = threadIdx.x; i < CHUNK4; i += 256) {
        v4i d = __builtin_nontemporal_load(&d4[i]);
        v4i s = __builtin_nontemporal_load(&s4[i]);
        if ((unsigned)(d.x - lo_node) < (unsigned)NODES_PER_SLICE)
            csr[atomicAdd(&cursor[d.x], 1)] = s.x;
        if ((unsigned)(d.y - lo_node) < (unsigned)NODES_PER_SLICE)
            csr[atomicAdd(&cursor[d.y], 1)] = s.y;
        if ((unsigned)(d.z - lo_node) < (unsigned)NODES_PER_SLICE)
            csr[atomicAdd(&cursor[d.z], 1)] = s.z;
        if ((unsigned)(d.w - lo_node) < (unsigned)NODES_PER_SLICE)
            csr[atomicAdd(&cursor[d.w], 1)] = s.w;
    }
}

// ---------------- g = (x @ W1) * dis : (N x 128) @ (128 x 32) ----------------
__global__ void gemm128_kernel(const float* __restrict__ x, const float* __restrict__ W,
                               const float* __restrict__ dis, float* __restrict__ out) {
    __shared__ float ws[128 * 32];
    __shared__ float xs[8][128];
    int tid = threadIdx.x;
    const float4* W4 = (const float4*)W;
    float4* ws4 = (float4*)ws;
    for (int i = tid; i < 1024; i += 256) ws4[i] = W4[i];
    int row0 = blockIdx.x * 8;
    const float4* x4 = (const float4*)(x + (size_t)row0 * N_FEAT);
    float4* xs4 = (float4*)xs;
    xs4[tid] = x4[tid];  // 256 float4 = 8 rows x 128
    __syncthreads();
    int r = tid >> 5, j = tid & 31;
    float acc = 0.f;
#pragma unroll
    for (int k = 0; k < 128; k++) acc += xs[r][k] * ws[k * 32 + j];
    out[(row0 + r) * H_DIM + j] = acc * dis[row0 + r];
}

// ---------------- g = (relu(in) @ W) * dis : (N x 32) @ (32 x 32) ----------------
template <bool RELU>
__global__ void gemm32_kernel(const float* __restrict__ in, const float* __restrict__ W,
                              const float* __restrict__ dis, float* __restrict__ out) {
    __shared__ float ws[32 * 32];
    __shared__ float xs[32][32];
    int tid = threadIdx.x;
    const float4* W4 = (const float4*)W;
    float4* ws4 = (float4*)ws;
    for (int i = tid; i < 256; i += 256) ws4[i] = W4[i];
    int row0 = blockIdx.x * 32;
    const float4* in4 = (const float4*)(in + (size_t)row0 * 32);
    float4 v = in4[tid];
    if (RELU) {
        v.x = fmaxf(v.x, 0.f); v.y = fmaxf(v.y, 0.f);
        v.z = fmaxf(v.z, 0.f); v.w = fmaxf(v.w, 0.f);
    }
    ((float4*)xs)[tid] = v;
    __syncthreads();
    int j = tid & 31;
    int r0 = tid >> 5;  // 0..7
    float acc[4] = {0.f, 0.f, 0.f, 0.f};
#pragma unroll
    for (int k = 0; k < 32; k++) {
        float w = ws[k * 32 + j];
#pragma unroll
        for (int m = 0; m < 4; m++) acc[m] += xs[r0 + 8 * m][k] * w;
    }
#pragma unroll
    for (int m = 0; m < 4; m++) {
        int row = row0 + r0 + 8 * m;
        out[row * 32 + j] = acc[m] * dis[row];
    }
}

// ---------------- gather: out[d] = dis[d]*(g[d] + sum g[src]) + b ----------------
// csr ids are a zero-reuse stream -> nt load keeps the g table L2-resident.
__global__ void gather_kernel(const int* __restrict__ rp, const int* __restrict__ csr,
                              const float* __restrict__ g, const float* __restrict__ dis,
                              const float* __restrict__ b, float* __restrict__ out) {
    int tid = threadIdx.x;
    int row = blockIdx.x * 8 + (tid >> 5);
    int j = tid & 31;
    int lo = rp[row], hi = rp[row + 1];
    float a0 = g[row * 32 + j];  // self loop: dis*g[d] = dis^2*h[d]
    float a1 = 0.f, a2 = 0.f, a3 = 0.f;
    for (int base = lo; base < hi; base += 32) {
        int cnt = hi - base; if (cnt > 32) cnt = 32;
        int sid = (base + j < hi) ? __builtin_nontemporal_load(&csr[base + j]) : 0;
        int k = 0;
        for (; k + 3 < cnt; k += 4) {
            int s0 = __shfl(sid, k, 32);
            int s1 = __shfl(sid, k + 1, 32);
            int s2 = __shfl(sid, k + 2, 32);
            int s3 = __shfl(sid, k + 3, 32);
            a0 += g[s0 * 32 + j];
            a1 += g[s1 * 32 + j];
            a2 += g[s2 * 32 + j];
            a3 += g[s3 * 32 + j];
        }
        for (; k < cnt; k++) {
            a0 += g[__shfl(sid, k, 32) * 32 + j];
        }
    }
    out[row * 32 + j] = dis[row] * (a0 + a1 + a2 + a3) + b[j];
}

// ---------------- fused mean-pool + linear + softmax ----------------
__global__ void pool_head_kernel(const float* __restrict__ h, const int* __restrict__ batch,
                                 const float* __restrict__ Wl, const float* __restrict__ bl,
                                 float* __restrict__ out) {
    __shared__ int seg[2];
    __shared__ float red[8][32];
    __shared__ float pooled[32];
    __shared__ float logits[N_CLASSES];
    int g = blockIdx.x, tid = threadIdx.x;
    if (tid == 0) {
        int lo = 0, hi = N_NODES;
        while (lo < hi) { int m = (lo + hi) >> 1; if (batch[m] < g) lo = m + 1; else hi = m; }
        seg[0] = lo;
        lo = seg[0]; hi = N_NODES;
        while (lo < hi) { int m = (lo + hi) >> 1; if (batch[m] < g + 1) lo = m + 1; else hi = m; }
        seg[1] = lo;
    }
    __syncthreads();
    int lo = seg[0], hi = seg[1];
    int j = tid & 31, rs = tid >> 5;
    float acc = 0.f;
    for (int i = lo + rs; i < hi; i += 8) acc += h[i * 32 + j];
    red[rs][j] = acc;
    __syncthreads();
    if (tid < 32) {
        float s = 0.f;
#pragma unroll
        for (int r = 0; r < 8; r++) s += red[r][j];
        float cnt = (float)(hi - lo);
        pooled[j] = s / fmaxf(cnt, 1.0f);
    }
    __syncthreads();
    if (tid < N_CLASSES) {
        float l = bl[tid];
#pragma unroll
        for (int k = 0; k < 32; k++) l += pooled[k] * Wl[k * N_CLASSES + tid];
        logits[tid] = l;
    }
    __syncthreads();
    if (tid < N_CLASSES) {
        float m = -1e30f;
#pragma unroll
        for (int c = 0; c < N_CLASSES; c++) m = fmaxf(m, logits[c]);
        float s = 0.f;
#pragma unroll
        for (int c = 0; c < N_CLASSES; c++) s += expf(logits[c] - m);
        out[g * N_CLASSES + tid] = expf(logits[tid] - m) / s;
    }
}

extern "C" void kernel_launch(void* const* d_in, const int* in_sizes, int n_in,
                              void* d_out, int out_size, void* d_ws, size_t ws_size,
                              hipStream_t stream) {
    const float* x     = (const float*)d_in[0];
    const int*   ei    = (const int*)d_in[1];
    const int*   batch = (const int*)d_in[2];
    const float* W1 = (const float*)d_in[3];
    const float* b1 = (const float*)d_in[4];
    const float* W2 = (const float*)d_in[5];
    const float* b2 = (const float*)d_in[6];
    const float* W3 = (const float*)d_in[7];
    const float* b3 = (const float*)d_in[8];
    const float* Wl = (const float*)d_in[9];
    const float* bl = (const float*)d_in[10];
    float* out = (float*)d_out;

    const int* src = ei;            // edge_index[0]
    const int* dst = ei + N_EDGES;  // edge_index[1]

    // workspace layout
    int*   wsi     = (int*)d_ws;
    int*   counts  = wsi;                        // N_NODES
    int*   row_ptr = counts + N_NODES;           // N_NODES + 1
    int*   cursor  = row_ptr + N_NODES + 1;      // N_NODES
    int*   bsums   = cursor + N_NODES;           // 512
    int*   csr     = bsums + 512;                // N_EDGES
    float* dis     = (float*)(csr + N_EDGES);    // N_NODES
    float* g       = dis + N_NODES;              // N_NODES * 32
    float* h_agg   = g + N_NODES * H_DIM;        // N_NODES * 32

    // ---- CSR build (also yields degree -> dis) ----
    zero_counts_kernel<<<NBLK, 256, 0, stream>>>(counts);
    hist_sliced_kernel<<<NS * GPS, 256, 0, stream>>>(dst, counts);
    scan_part1_kernel<<<NBLK, 256, 0, stream>>>(counts, bsums);
    scan_part2_kernel<<<1, 512, 0, stream>>>(bsums);
    scan_part3_kernel<<<NBLK, 256, 0, stream>>>(counts, bsums, row_ptr, cursor, dis);
    fill_sliced_kernel<<<NS * GPS, 256, 0, stream>>>(src, dst, cursor, csr);

    // ---- layer 1 ----
    gemm128_kernel<<<N_NODES / 8, 256, 0, stream>>>(x, W1, dis, g);
    gather_kernel<<<N_NODES / 8, 256, 0, stream>>>(row_ptr, csr, g, dis, b1, h_agg);

    // ---- layer 2 ----
    gemm32_kernel<true><<<N_NODES / 32, 256, 0, stream>>>(h_agg, W2, dis, g);
    gather_kernel<<<N_NODES / 8, 256, 0, stream>>>(row_ptr, csr, g, dis, b2, h_agg);

    // ---- layer 3 ----
    gemm32_kernel<true><<<N_NODES / 32, 256, 0, stream>>>(h_agg, W3, dis, g);
    gather_kernel<<<N_NODES / 8, 256, 0, stream>>>(row_ptr, csr, g, dis, b3, h_agg);

    // ---- pool + classifier + softmax ----
    pool_head_kernel<<<N_GRAPHS, 256, 0, stream>>>(h_agg, batch, Wl, bl, out);
}

// Round 10
// 410.241 us; speedup vs baseline: 1.2549x; 1.2549x over previous
//
#include <hip/hip_runtime.h>
#include <math.h>

#define N_NODES   100000
#define N_EDGES   1600000
#define N_FEAT    128
#define H_DIM     32
#define N_CLASSES 10
#define N_GRAPHS  64

// ---- radix-partition CSR build parameters ----
#define P_CHUNK   400                        // edge chunks
#define EPC       (N_EDGES / P_CHUNK)        // 4000 edges/chunk
#define EPC4      (EPC / 4)                  // 1000 x 16B
#define B_SHIFT   9
#define NPB       512                        // nodes per bucket
#define NBK       ((N_NODES + NPB - 1) / NPB)  // 196 buckets

typedef int v4i __attribute__((ext_vector_type(4)));

// ---- Pass A: per-chunk bucket histogram (LDS), C[c][b] ----
__global__ void radix_hist_kernel(const int* __restrict__ dst, int* __restrict__ C) {
    __shared__ int hcnt[NBK];
    int c = blockIdx.x, tid = threadIdx.x;
    for (int i = tid; i < NBK; i += 256) hcnt[i] = 0;
    __syncthreads();
    const v4i* d4 = (const v4i*)(dst + c * EPC);
    for (int i = tid; i < EPC4; i += 256) {
        v4i d = __builtin_nontemporal_load(&d4[i]);
        atomicAdd(&hcnt[d.x >> B_SHIFT], 1);
        atomicAdd(&hcnt[d.y >> B_SHIFT], 1);
        atomicAdd(&hcnt[d.z >> B_SHIFT], 1);
        atomicAdd(&hcnt[d.w >> B_SHIFT], 1);
    }
    __syncthreads();
    for (int b = tid; b < NBK; b += 256) C[c * NBK + b] = hcnt[b];
}

// ---- S1: per-bucket exclusive scan over chunks; PO[c][b], bt[b] ----
__global__ void radix_scan1_kernel(const int* __restrict__ C, int* __restrict__ PO,
                                   int* __restrict__ bt) {
    __shared__ int s[512];
    int b = blockIdx.x, t = threadIdx.x;  // blockDim = 512
    int v = (t < P_CHUNK) ? C[t * NBK + b] : 0;
    s[t] = v;
    __syncthreads();
    for (int off = 1; off < 512; off <<= 1) {
        int x = (t >= off) ? s[t - off] : 0;
        __syncthreads();
        s[t] += x;
        __syncthreads();
    }
    if (t < P_CHUNK) PO[t * NBK + b] = s[t] - v;  // exclusive within bucket
    if (t == 511) bt[b] = s[511];                 // bucket total
}

// ---- S2: exclusive scan of bucket totals -> bb[] ----
__global__ void radix_scan2_kernel(const int* __restrict__ bt, int* __restrict__ bb) {
    __shared__ int s[256];
    int t = threadIdx.x;  // blockDim = 256
    int v = (t < NBK) ? bt[t] : 0;
    s[t] = v;
    __syncthreads();
    for (int off = 1; off < 256; off <<= 1) {
        int x = (t >= off) ? s[t - off] : 0;
        __syncthreads();
        s[t] += x;
        __syncthreads();
    }
    if (t < NBK) bb[t] = s[t] - v;
    if (t == 0) bb[NBK] = N_EDGES;
}

// ---- Pass B: scatter (src,dst) pairs into bucket-major runs ----
// chunk c's bucket-b run is ~20 contiguous int2 -> near-perfect write merge.
__global__ void radix_scatter_kernel(const int* __restrict__ src, const int* __restrict__ dst,
                                     const int* __restrict__ PO, const int* __restrict__ bb,
                                     int2* __restrict__ pairs) {
    __shared__ int cur[NBK];
    int c = blockIdx.x, tid = threadIdx.x;
    for (int b = tid; b < NBK; b += 256) cur[b] = bb[b] + PO[c * NBK + b];
    __syncthreads();
    const v4i* d4 = (const v4i*)(dst + c * EPC);
    const v4i* s4 = (const v4i*)(src + c * EPC);
    for (int i = tid; i < EPC4; i += 256) {
        v4i d = __builtin_nontemporal_load(&d4[i]);
        v4i s = __builtin_nontemporal_load(&s4[i]);
        int2 p;
        int pos;
        pos = atomicAdd(&cur[d.x >> B_SHIFT], 1); p.x = s.x; p.y = d.x; pairs[pos] = p;
        pos = atomicAdd(&cur[d.y >> B_SHIFT], 1); p.x = s.y; p.y = d.y; pairs[pos] = p;
        pos = atomicAdd(&cur[d.z >> B_SHIFT], 1); p.x = s.z; p.y = d.z; pairs[pos] = p;
        pos = atomicAdd(&cur[d.w >> B_SHIFT], 1); p.x = s.w; p.y = d.w; pairs[pos] = p;
    }
}

// ---- Pass C: one block per bucket: count per node, LDS scan -> row_ptr/dis,
// then scatter src ids into the bucket's contiguous csr region. ----
__global__ void radix_final_kernel(const int2* __restrict__ pairs, const int* __restrict__ bb,
                                   int* __restrict__ row_ptr, float* __restrict__ dis,
                                   int* __restrict__ csr) {
    __shared__ int cnt[NPB];
    __shared__ int s[NPB];
    int b = blockIdx.x, n = threadIdx.x;  // blockDim = NPB = 512
    int node0 = b << B_SHIFT;
    int lo = bb[b], hi = bb[b + 1];
    cnt[n] = 0;
    __syncthreads();
    for (int i = lo + n; i < hi; i += NPB)
        atomicAdd(&cnt[pairs[i].y - node0], 1);
    __syncthreads();
    int deg = cnt[n];
    s[n] = deg;
    __syncthreads();
    for (int off = 1; off < NPB; off <<= 1) {
        int x = (n >= off) ? s[n - off] : 0;
        __syncthreads();
        s[n] += x;
        __syncthreads();
    }
    int start = s[n] - deg;  // exclusive prefix within bucket
    int node = node0 + n;
    if (node < N_NODES) {
        row_ptr[node] = lo + start;
        dis[node] = rsqrtf((float)deg + 1.0f);
    }
    if (b == NBK - 1 && n == 0) row_ptr[N_NODES] = N_EDGES;
    __syncthreads();
    cnt[n] = start;  // reuse as cursor
    __syncthreads();
    for (int i = lo + n; i < hi; i += NPB) {
        int2 p = pairs[i];
        int pos = lo + atomicAdd(&cnt[p.y - node0], 1);
        csr[pos] = p.x;
    }
}

// ---------------- g = (x @ W1) * dis : (N x 128) @ (128 x 32) ----------------
__global__ void gemm128_kernel(const float* __restrict__ x, const float* __restrict__ W,
                               const float* __restrict__ dis, float* __restrict__ out) {
    __shared__ float ws[128 * 32];
    __shared__ float xs[8][128];
    int tid = threadIdx.x;
    const float4* W4 = (const float4*)W;
    float4* ws4 = (float4*)ws;
    for (int i = tid; i < 1024; i += 256) ws4[i] = W4[i];
    int row0 = blockIdx.x * 8;
    const float4* x4 = (const float4*)(x + (size_t)row0 * N_FEAT);
    float4* xs4 = (float4*)xs;
    xs4[tid] = x4[tid];  // 256 float4 = 8 rows x 128
    __syncthreads();
    int r = tid >> 5, j = tid & 31;
    float acc = 0.f;
#pragma unroll
    for (int k = 0; k < 128; k++) acc += xs[r][k] * ws[k * 32 + j];
    out[(row0 + r) * H_DIM + j] = acc * dis[row0 + r];
}

// ---------------- g = (relu(in) @ W) * dis : (N x 32) @ (32 x 32) ----------------
template <bool RELU>
__global__ void gemm32_kernel(const float* __restrict__ in, const float* __restrict__ W,
                              const float* __restrict__ dis, float* __restrict__ out) {
    __shared__ float ws[32 * 32];
    __shared__ float xs[32][32];
    int tid = threadIdx.x;
    const float4* W4 = (const float4*)W;
    float4* ws4 = (float4*)ws;
    for (int i = tid; i < 256; i += 256) ws4[i] = W4[i];
    int row0 = blockIdx.x * 32;
    const float4* in4 = (const float4*)(in + (size_t)row0 * 32);
    float4 v = in4[tid];
    if (RELU) {
        v.x = fmaxf(v.x, 0.f); v.y = fmaxf(v.y, 0.f);
        v.z = fmaxf(v.z, 0.f); v.w = fmaxf(v.w, 0.f);
    }
    ((float4*)xs)[tid] = v;
    __syncthreads();
    int j = tid & 31;
    int r0 = tid >> 5;  // 0..7
    float acc[4] = {0.f, 0.f, 0.f, 0.f};
#pragma unroll
    for (int k = 0; k < 32; k++) {
        float w = ws[k * 32 + j];
#pragma unroll
        for (int m = 0; m < 4; m++) acc[m] += xs[r0 + 8 * m][k] * w;
    }
#pragma unroll
    for (int m = 0; m < 4; m++) {
        int row = row0 + r0 + 8 * m;
        out[row * 32 + j] = acc[m] * dis[row];
    }
}

// ---------------- gather: out[d] = dis[d]*(g[d] + sum g[src]) + b ----------------
__global__ void gather_kernel(const int* __restrict__ rp, const int* __restrict__ csr,
                              const float* __restrict__ g, const float* __restrict__ dis,
                              const float* __restrict__ b, float* __restrict__ out) {
    int tid = threadIdx.x;
    int row = blockIdx.x * 8 + (tid >> 5);
    int j = tid & 31;
    int lo = rp[row], hi = rp[row + 1];
    float a0 = g[row * 32 + j];  // self loop: dis*g[d] = dis^2*h[d]
    float a1 = 0.f, a2 = 0.f, a3 = 0.f;
    for (int base = lo; base < hi; base += 32) {
        int cnt = hi - base; if (cnt > 32) cnt = 32;
        int sid = (base + j < hi) ? __builtin_nontemporal_load(&csr[base + j]) : 0;
        int k = 0;
        for (; k + 3 < cnt; k += 4) {
            int s0 = __shfl(sid, k, 32);
            int s1 = __shfl(sid, k + 1, 32);
            int s2 = __shfl(sid, k + 2, 32);
            int s3 = __shfl(sid, k + 3, 32);
            a0 += g[s0 * 32 + j];
            a1 += g[s1 * 32 + j];
            a2 += g[s2 * 32 + j];
            a3 += g[s3 * 32 + j];
        }
        for (; k < cnt; k++) {
            a0 += g[__shfl(sid, k, 32) * 32 + j];
        }
    }
    out[row * 32 + j] = dis[row] * (a0 + a1 + a2 + a3) + b[j];
}

// ---------------- fused mean-pool + linear + softmax ----------------
__global__ void pool_head_kernel(const float* __restrict__ h, const int* __restrict__ batch,
                                 const float* __restrict__ Wl, const float* __restrict__ bl,
                                 float* __restrict__ out) {
    __shared__ int seg[2];
    __shared__ float red[8][32];
    __shared__ float pooled[32];
    __shared__ float logits[N_CLASSES];
    int g = blockIdx.x, tid = threadIdx.x;
    if (tid == 0) {
        int lo = 0, hi = N_NODES;
        while (lo < hi) { int m = (lo + hi) >> 1; if (batch[m] < g) lo = m + 1; else hi = m; }
        seg[0] = lo;
        lo = seg[0]; hi = N_NODES;
        while (lo < hi) { int m = (lo + hi) >> 1; if (batch[m] < g + 1) lo = m + 1; else hi = m; }
        seg[1] = lo;
    }
    __syncthreads();
    int lo = seg[0], hi = seg[1];
    int j = tid & 31, rs = tid >> 5;
    float acc = 0.f;
    for (int i = lo + rs; i < hi; i += 8) acc += h[i * 32 + j];
    red[rs][j] = acc;
    __syncthreads();
    if (tid < 32) {
        float s = 0.f;
#pragma unroll
        for (int r = 0; r < 8; r++) s += red[r][j];
        float cnt = (float)(hi - lo);
        pooled[j] = s / fmaxf(cnt, 1.0f);
    }
    __syncthreads();
    if (tid < N_CLASSES) {
        float l = bl[tid];
#pragma unroll
        for (int k = 0; k < 32; k++) l += pooled[k] * Wl[k * N_CLASSES + tid];
        logits[tid] = l;
    }
    __syncthreads();
    if (tid < N_CLASSES) {
        float m = -1e30f;
#pragma unroll
        for (int c = 0; c < N_CLASSES; c++) m = fmaxf(m, logits[c]);
        float s = 0.f;
#pragma unroll
        for (int c = 0; c < N_CLASSES; c++) s += expf(logits[c] - m);
        out[g * N_CLASSES + tid] = expf(logits[tid] - m) / s;
    }
}

extern "C" void kernel_launch(void* const* d_in, const int* in_sizes, int n_in,
                              void* d_out, int out_size, void* d_ws, size_t ws_size,
                              hipStream_t stream) {
    const float* x     = (const float*)d_in[0];
    const int*   ei    = (const int*)d_in[1];
    const int*   batch = (const int*)d_in[2];
    const float* W1 = (const float*)d_in[3];
    const float* b1 = (const float*)d_in[4];
    const float* W2 = (const float*)d_in[5];
    const float* b2 = (const float*)d_in[6];
    const float* W3 = (const float*)d_in[7];
    const float* b3 = (const float*)d_in[8];
    const float* Wl = (const float*)d_in[9];
    const float* bl = (const float*)d_in[10];
    float* out = (float*)d_out;

    const int* src = ei;            // edge_index[0]
    const int* dst = ei + N_EDGES;  // edge_index[1]

    // workspace layout (ints unless noted). pairs aliases g: pairs is dead
    // after radix_final; g is first written by gemm128 afterwards (same stream).
    int*   wsi     = (int*)d_ws;
    int*   C       = wsi;                         // P_CHUNK*NBK = 78400
    int*   PO      = C + P_CHUNK * NBK;           // 78400
    int*   bt      = PO + P_CHUNK * NBK;          // NBK
    int*   bb      = bt + NBK;                    // NBK+1
    int*   row_ptr = bb + NBK + 1;                // N_NODES+1
    float* dis     = (float*)(row_ptr + N_NODES + 1);  // N_NODES
    int*   csr     = (int*)(dis + N_NODES);       // N_EDGES
    int2*  pairs   = (int2*)(csr + N_EDGES);      // N_EDGES int2 (12.8 MB)
    float* g       = (float*)pairs;               // alias: N_NODES*32 floats
    float* h_agg   = (float*)(csr + N_EDGES) + 2 * N_EDGES;  // N_NODES*32

    // ---- CSR build: 2-level radix partition (also yields row_ptr, dis) ----
    radix_hist_kernel<<<P_CHUNK, 256, 0, stream>>>(dst, C);
    radix_scan1_kernel<<<NBK, 512, 0, stream>>>(C, PO, bt);
    radix_scan2_kernel<<<1, 256, 0, stream>>>(bt, bb);
    radix_scatter_kernel<<<P_CHUNK, 256, 0, stream>>>(src, dst, PO, bb, pairs);
    radix_final_kernel<<<NBK, NPB, 0, stream>>>(pairs, bb, row_ptr, dis, csr);

    // ---- layer 1 ----
    gemm128_kernel<<<N_NODES / 8, 256, 0, stream>>>(x, W1, dis, g);
    gather_kernel<<<N_NODES / 8, 256, 0, stream>>>(row_ptr, csr, g, dis, b1, h_agg);

    // ---- layer 2 ----
    gemm32_kernel<true><<<N_NODES / 32, 256, 0, stream>>>(h_agg, W2, dis, g);
    gather_kernel<<<N_NODES / 8, 256, 0, stream>>>(row_ptr, csr, g, dis, b2, h_agg);

    // ---- layer 3 ----
    gemm32_kernel<true><<<N_NODES / 32, 256, 0, stream>>>(h_agg, W3, dis, g);
    gather_kernel<<<N_NODES / 8, 256, 0, stream>>>(row_ptr, csr, g, dis, b3, h_agg);

    // ---- pool + classifier + softmax ----
    pool_head_kernel<<<N_GRAPHS, 256, 0, stream>>>(h_agg, batch, Wl, bl, out);
}

// Round 16
// 375.814 us; speedup vs baseline: 1.3698x; 1.0916x over previous
//
#include <hip/hip_runtime.h>
#include <math.h>

#define N_NODES   100000
#define N_EDGES   1600000
#define N_FEAT    128
#define H_DIM     32
#define N_CLASSES 10
#define N_GRAPHS  64

// ---- radix-partition CSR build parameters ----
#define P_CHUNK   400                        // edge chunks
#define EPC       (N_EDGES / P_CHUNK)        // 4000 edges/chunk
#define EPC4      (EPC / 4)                  // 1000 x 16B
#define B_SHIFT   9
#define NPB       512                        // nodes per bucket
#define NBK       ((N_NODES + NPB - 1) / NPB)  // 196 buckets

// ---- pooling ----
#define PNPB      256                        // nodes per pool-partial block
#define PBLK      ((N_NODES + PNPB - 1) / PNPB)  // 391

typedef int v4i __attribute__((ext_vector_type(4)));

// ---- Pass A: per-chunk bucket histogram (LDS), C[c][b] ----
__global__ void radix_hist_kernel(const int* __restrict__ dst, int* __restrict__ C) {
    __shared__ int hcnt[NBK];
    int c = blockIdx.x, tid = threadIdx.x;
    for (int i = tid; i < NBK; i += 256) hcnt[i] = 0;
    __syncthreads();
    const v4i* d4 = (const v4i*)(dst + c * EPC);
    for (int i = tid; i < EPC4; i += 256) {
        v4i d = __builtin_nontemporal_load(&d4[i]);
        atomicAdd(&hcnt[d.x >> B_SHIFT], 1);
        atomicAdd(&hcnt[d.y >> B_SHIFT], 1);
        atomicAdd(&hcnt[d.z >> B_SHIFT], 1);
        atomicAdd(&hcnt[d.w >> B_SHIFT], 1);
    }
    __syncthreads();
    for (int b = tid; b < NBK; b += 256) C[c * NBK + b] = hcnt[b];
}

// ---- S1: per-bucket exclusive scan over chunks; PO[c][b], bt[b] ----
__global__ void radix_scan1_kernel(const int* __restrict__ C, int* __restrict__ PO,
                                   int* __restrict__ bt) {
    __shared__ int s[512];
    int b = blockIdx.x, t = threadIdx.x;  // blockDim = 512
    int v = (t < P_CHUNK) ? C[t * NBK + b] : 0;
    s[t] = v;
    __syncthreads();
    for (int off = 1; off < 512; off <<= 1) {
        int x = (t >= off) ? s[t - off] : 0;
        __syncthreads();
        s[t] += x;
        __syncthreads();
    }
    if (t < P_CHUNK) PO[t * NBK + b] = s[t] - v;  // exclusive within bucket
    if (t == 511) bt[b] = s[511];                 // bucket total
}

// ---- S2: exclusive scan of bucket totals -> bb[]; also zeroes pool accum ----
__global__ void radix_scan2_kernel(const int* __restrict__ bt, int* __restrict__ bb,
                                   float* __restrict__ gacc) {
    __shared__ int s[256];
    int t = threadIdx.x;  // blockDim = 256
    int v = (t < NBK) ? bt[t] : 0;
    s[t] = v;
    __syncthreads();
    for (int off = 1; off < 256; off <<= 1) {
        int x = (t >= off) ? s[t - off] : 0;
        __syncthreads();
        s[t] += x;
        __syncthreads();
    }
    if (t < NBK) bb[t] = s[t] - v;
    if (t == 0) bb[NBK] = N_EDGES;
    for (int i = t; i < N_GRAPHS * H_DIM; i += 256) gacc[i] = 0.f;
}

// ---- Pass B: scatter (src,dst) pairs into bucket-major runs ----
__global__ void radix_scatter_kernel(const int* __restrict__ src, const int* __restrict__ dst,
                                     const int* __restrict__ PO, const int* __restrict__ bb,
                                     int2* __restrict__ pairs) {
    __shared__ int cur[NBK];
    int c = blockIdx.x, tid = threadIdx.x;
    for (int b = tid; b < NBK; b += 256) cur[b] = bb[b] + PO[c * NBK + b];
    __syncthreads();
    const v4i* d4 = (const v4i*)(dst + c * EPC);
    const v4i* s4 = (const v4i*)(src + c * EPC);
    for (int i = tid; i < EPC4; i += 256) {
        v4i d = __builtin_nontemporal_load(&d4[i]);
        v4i s = __builtin_nontemporal_load(&s4[i]);
        int2 p;
        int pos;
        pos = atomicAdd(&cur[d.x >> B_SHIFT], 1); p.x = s.x; p.y = d.x; pairs[pos] = p;
        pos = atomicAdd(&cur[d.y >> B_SHIFT], 1); p.x = s.y; p.y = d.y; pairs[pos] = p;
        pos = atomicAdd(&cur[d.z >> B_SHIFT], 1); p.x = s.z; p.y = d.z; pairs[pos] = p;
        pos = atomicAdd(&cur[d.w >> B_SHIFT], 1); p.x = s.w; p.y = d.w; pairs[pos] = p;
    }
}

// ---- Pass C: one block per bucket: count, LDS scan -> row_ptr/dis, scatter csr ----
__global__ void radix_final_kernel(const int2* __restrict__ pairs, const int* __restrict__ bb,
                                   int* __restrict__ row_ptr, float* __restrict__ dis,
                                   int* __restrict__ csr) {
    __shared__ int cnt[NPB];
    __shared__ int s[NPB];
    int b = blockIdx.x, n = threadIdx.x;  // blockDim = NPB = 512
    int node0 = b << B_SHIFT;
    int lo = bb[b], hi = bb[b + 1];
    cnt[n] = 0;
    __syncthreads();
    for (int i = lo + n; i < hi; i += NPB)
        atomicAdd(&cnt[pairs[i].y - node0], 1);
    __syncthreads();
    int deg = cnt[n];
    s[n] = deg;
    __syncthreads();
    for (int off = 1; off < NPB; off <<= 1) {
        int x = (n >= off) ? s[n - off] : 0;
        __syncthreads();
        s[n] += x;
        __syncthreads();
    }
    int start = s[n] - deg;  // exclusive prefix within bucket
    int node = node0 + n;
    if (node < N_NODES) {
        row_ptr[node] = lo + start;
        dis[node] = rsqrtf((float)deg + 1.0f);
    }
    if (b == NBK - 1 && n == 0) row_ptr[N_NODES] = N_EDGES;
    __syncthreads();
    cnt[n] = start;  // reuse as cursor
    __syncthreads();
    for (int i = lo + n; i < hi; i += NPB) {
        int2 p = pairs[i];
        int pos = lo + atomicAdd(&cnt[p.y - node0], 1);
        csr[pos] = p.x;
    }
}

// ---------------- g = (x @ W1) * dis : (N x 128) @ (128 x 32) ----------------
__global__ void gemm128_kernel(const float* __restrict__ x, const float* __restrict__ W,
                               const float* __restrict__ dis, float* __restrict__ out) {
    __shared__ float ws[128 * 32];
    __shared__ float xs[8][128];
    int tid = threadIdx.x;
    const float4* W4 = (const float4*)W;
    float4* ws4 = (float4*)ws;
    for (int i = tid; i < 1024; i += 256) ws4[i] = W4[i];
    int row0 = blockIdx.x * 8;
    const float4* x4 = (const float4*)(x + (size_t)row0 * N_FEAT);
    float4* xs4 = (float4*)xs;
    xs4[tid] = x4[tid];  // 256 float4 = 8 rows x 128
    __syncthreads();
    int r = tid >> 5, j = tid & 31;
    float acc = 0.f;
#pragma unroll
    for (int k = 0; k < 128; k++) acc += xs[r][k] * ws[k * 32 + j];
    out[(row0 + r) * H_DIM + j] = acc * dis[row0 + r];
}

// ---------------- g = (relu(in) @ W) * dis : (N x 32) @ (32 x 32) ----------------
template <bool RELU>
__global__ void gemm32_kernel(const float* __restrict__ in, const float* __restrict__ W,
                              const float* __restrict__ dis, float* __restrict__ out) {
    __shared__ float ws[32 * 32];
    __shared__ float xs[32][32];
    int tid = threadIdx.x;
    const float4* W4 = (const float4*)W;
    float4* ws4 = (float4*)ws;
    for (int i = tid; i < 256; i += 256) ws4[i] = W4[i];
    int row0 = blockIdx.x * 32;
    const float4* in4 = (const float4*)(in + (size_t)row0 * 32);
    float4 v = in4[tid];
    if (RELU) {
        v.x = fmaxf(v.x, 0.f); v.y = fmaxf(v.y, 0.f);
        v.z = fmaxf(v.z, 0.f); v.w = fmaxf(v.w, 0.f);
    }
    ((float4*)xs)[tid] = v;
    __syncthreads();
    int j = tid & 31;
    int r0 = tid >> 5;  // 0..7
    float acc[4] = {0.f, 0.f, 0.f, 0.f};
#pragma unroll
    for (int k = 0; k < 32; k++) {
        float w = ws[k * 32 + j];
#pragma unroll
        for (int m = 0; m < 4; m++) acc[m] += xs[r0 + 8 * m][k] * w;
    }
#pragma unroll
    for (int m = 0; m < 4; m++) {
        int row = row0 + r0 + 8 * m;
        out[row * 32 + j] = acc[m] * dis[row];
    }
}

// ---------------- gather: out[d] = dis[d]*(g[d] + sum g[src]) + b ----------------
__global__ void gather_kernel(const int* __restrict__ rp, const int* __restrict__ csr,
                              const float* __restrict__ g, const float* __restrict__ dis,
                              const float* __restrict__ b, float* __restrict__ out) {
    int tid = threadIdx.x;
    int row = blockIdx.x * 8 + (tid >> 5);
    int j = tid & 31;
    int lo = rp[row], hi = rp[row + 1];
    float a0 = g[row * 32 + j];  // self loop: dis*g[d] = dis^2*h[d]
    float a1 = 0.f, a2 = 0.f, a3 = 0.f;
    for (int base = lo; base < hi; base += 32) {
        int cnt = hi - base; if (cnt > 32) cnt = 32;
        int sid = (base + j < hi) ? __builtin_nontemporal_load(&csr[base + j]) : 0;
        int k = 0;
        for (; k + 3 < cnt; k += 4) {
            int s0 = __shfl(sid, k, 32);
            int s1 = __shfl(sid, k + 1, 32);
            int s2 = __shfl(sid, k + 2, 32);
            int s3 = __shfl(sid, k + 3, 32);
            a0 += g[s0 * 32 + j];
            a1 += g[s1 * 32 + j];
            a2 += g[s2 * 32 + j];
            a3 += g[s3 * 32 + j];
        }
        for (; k < cnt; k++) {
            a0 += g[__shfl(sid, k, 32) * 32 + j];
        }
    }
    out[row * 32 + j] = dis[row] * (a0 + a1 + a2 + a3) + b[j];
}

// ---------------- pool phase 1: per-256-node partial sums -> gacc atomics ----------------
// batch is sorted: a 256-node window spans <=2 graphs (slot change <=2 per thread).
__global__ void pool_partial_kernel(const float* __restrict__ h, const int* __restrict__ batch,
                                    float* __restrict__ gacc) {
    __shared__ float acc_l[8][32];
    __shared__ int ginfo[2];
    int tid = threadIdx.x;
    int n0 = blockIdx.x * PNPB;
    if (tid < 256) ((float*)acc_l)[tid] = 0.f;
    if (tid == 0) {
        ginfo[0] = batch[n0];
        int last = n0 + PNPB; if (last > N_NODES) last = N_NODES;
        ginfo[1] = batch[last - 1];
    }
    __syncthreads();
    int g_lo = ginfo[0], g_hi = ginfo[1];
    int j = tid & 31;
    float racc = 0.f;
    int cslot = -1;
    for (int rr = tid >> 5; rr < PNPB; rr += 8) {
        int row = n0 + rr;
        if (row >= N_NODES) break;
        int slot = batch[row] - g_lo;
        if (slot != cslot) {
            if (cslot >= 0) {
                if (cslot < 8) atomicAdd(&acc_l[cslot][j], racc);
                else atomicAdd(&gacc[(g_lo + cslot) * H_DIM + j], racc);
            }
            racc = 0.f;
            cslot = slot;
        }
        racc += h[row * H_DIM + j];
    }
    if (cslot >= 0) {
        if (cslot < 8) atomicAdd(&acc_l[cslot][j], racc);
        else atomicAdd(&gacc[(g_lo + cslot) * H_DIM + j], racc);
    }
    __syncthreads();
    int nslots = g_hi - g_lo + 1; if (nslots > 8) nslots = 8;
    int slot = tid >> 5;
    if (slot < nslots && g_lo + slot < N_GRAPHS)
        atomicAdd(&gacc[(g_lo + slot) * H_DIM + j], acc_l[slot][j]);
}

// ---------------- pool phase 2: mean + linear + softmax (one block/graph) ----------------
__global__ void pool_final_kernel(const float* __restrict__ gacc, const int* __restrict__ batch,
                                  const float* __restrict__ Wl, const float* __restrict__ bl,
                                  float* __restrict__ out) {
    __shared__ float pooled[H_DIM];
    __shared__ float logits[N_CLASSES];
    __shared__ int segc;
    int g = blockIdx.x, tid = threadIdx.x;  // blockDim = 64
    if (tid == 0) {
        int lo = 0, hi = N_NODES;
        while (lo < hi) { int m = (lo + hi) >> 1; if (batch[m] < g) lo = m + 1; else hi = m; }
        int a = lo;
        lo = a; hi = N_NODES;
        while (lo < hi) { int m = (lo + hi) >> 1; if (batch[m] < g + 1) lo = m + 1; else hi = m; }
        segc = lo - a;
    }
    __syncthreads();
    if (tid < H_DIM) pooled[tid] = gacc[g * H_DIM + tid] / fmaxf((float)segc, 1.0f);
    __syncthreads();
    if (tid < N_CLASSES) {
        float l = bl[tid];
#pragma unroll
        for (int k = 0; k < H_DIM; k++) l += pooled[k] * Wl[k * N_CLASSES + tid];
        logits[tid] = l;
    }
    __syncthreads();
    if (tid < N_CLASSES) {
        float m = -1e30f;
#pragma unroll
        for (int c = 0; c < N_CLASSES; c++) m = fmaxf(m, logits[c]);
        float s = 0.f;
#pragma unroll
        for (int c = 0; c < N_CLASSES; c++) s += expf(logits[c] - m);
        out[g * N_CLASSES + tid] = expf(logits[tid] - m) / s;
    }
}

extern "C" void kernel_launch(void* const* d_in, const int* in_sizes, int n_in,
                              void* d_out, int out_size, void* d_ws, size_t ws_size,
                              hipStream_t stream) {
    const float* x     = (const float*)d_in[0];
    const int*   ei    = (const int*)d_in[1];
    const int*   batch = (const int*)d_in[2];
    const float* W1 = (const float*)d_in[3];
    const float* b1 = (const float*)d_in[4];
    const float* W2 = (const float*)d_in[5];
    const float* b2 = (const float*)d_in[6];
    const float* W3 = (const float*)d_in[7];
    const float* b3 = (const float*)d_in[8];
    const float* Wl = (const float*)d_in[9];
    const float* bl = (const float*)d_in[10];
    float* out = (float*)d_out;

    const int* src = ei;            // edge_index[0]
    const int* dst = ei + N_EDGES;  // edge_index[1]

    // workspace layout (ints unless noted). pairs aliases g: pairs is dead
    // after radix_final; g is first written by gemm128 afterwards (same stream).
    int*   wsi     = (int*)d_ws;
    int*   C       = wsi;                         // P_CHUNK*NBK = 78400
    int*   PO      = C + P_CHUNK * NBK;           // 78400
    int*   bt      = PO + P_CHUNK * NBK;          // NBK
    int*   bb      = bt + NBK;                    // NBK+1
    int*   row_ptr = bb + NBK + 1;                // N_NODES+1
    float* dis     = (float*)(row_ptr + N_NODES + 1);  // N_NODES
    int*   csr     = (int*)(dis + N_NODES);       // N_EDGES
    int2*  pairs   = (int2*)(csr + N_EDGES);      // N_EDGES int2 (12.8 MB)
    float* g       = (float*)pairs;               // alias: N_NODES*32 floats
    float* h_agg   = (float*)(csr + N_EDGES) + 2 * N_EDGES;  // N_NODES*32
    float* gacc    = h_agg + N_NODES * H_DIM;     // N_GRAPHS*32

    // ---- CSR build: 2-level radix partition (also yields row_ptr, dis) ----
    radix_hist_kernel<<<P_CHUNK, 256, 0, stream>>>(dst, C);
    radix_scan1_kernel<<<NBK, 512, 0, stream>>>(C, PO, bt);
    radix_scan2_kernel<<<1, 256, 0, stream>>>(bt, bb, gacc);
    radix_scatter_kernel<<<P_CHUNK, 256, 0, stream>>>(src, dst, PO, bb, pairs);
    radix_final_kernel<<<NBK, NPB, 0, stream>>>(pairs, bb, row_ptr, dis, csr);

    // ---- layer 1 ----
    gemm128_kernel<<<N_NODES / 8, 256, 0, stream>>>(x, W1, dis, g);
    gather_kernel<<<N_NODES / 8, 256, 0, stream>>>(row_ptr, csr, g, dis, b1, h_agg);

    // ---- layer 2 ----
    gemm32_kernel<true><<<N_NODES / 32, 256, 0, stream>>>(h_agg, W2, dis, g);
    gather_kernel<<<N_NODES / 8, 256, 0, stream>>>(row_ptr, csr, g, dis, b2, h_agg);

    // ---- layer 3 ----
    gemm32_kernel<true><<<N_NODES / 32, 256, 0, stream>>>(h_agg, W3, dis, g);
    gather_kernel<<<N_NODES / 8, 256, 0, stream>>>(row_ptr, csr, g, dis, b3, h_agg);

    // ---- pool: two-phase ----
    pool_partial_kernel<<<PBLK, 256, 0, stream>>>(h_agg, batch, gacc);
    pool_final_kernel<<<N_GRAPHS, 64, 0, stream>>>(gacc, batch, Wl, bl, out);
}

// Round 17
// 336.537 us; speedup vs baseline: 1.5297x; 1.1167x over previous
//
#include <hip/hip_runtime.h>
#include <math.h>

#define N_NODES   100000
#define N_EDGES   1600000
#define N_FEAT    128
#define H_DIM     32
#define N_CLASSES 10
#define N_GRAPHS  64

// ---- radix-partition CSR build parameters ----
#define P_CHUNK   400                        // edge chunks
#define EPC       (N_EDGES / P_CHUNK)        // 4000 edges/chunk
#define EPC4      (EPC / 4)                  // 1000 x 16B
#define B_SHIFT   9
#define NPB       512                        // nodes per bucket
#define NBK       ((N_NODES + NPB - 1) / NPB)  // 196 buckets

// ---- pooling ----
#define PNPB      256                        // nodes per pool-partial block
#define PBLK      ((N_NODES + PNPB - 1) / PNPB)  // 391

typedef int v4i __attribute__((ext_vector_type(4)));
typedef unsigned short ushort_t;

// bf16 pack/unpack (round-to-nearest-even)
__device__ __forceinline__ ushort_t f2bf(float f) {
    union { float f; unsigned u; } v; v.f = f;
    unsigned r = v.u + 0x7FFFu + ((v.u >> 16) & 1u);
    return (ushort_t)(r >> 16);
}
__device__ __forceinline__ float bf2f(ushort_t h) {
    union { unsigned u; float f; } v; v.u = ((unsigned)h) << 16;
    return v.f;
}

// ---- Pass A: per-chunk bucket histogram (LDS), C[c][b] ----
__global__ void radix_hist_kernel(const int* __restrict__ dst, int* __restrict__ C) {
    __shared__ int hcnt[NBK];
    int c = blockIdx.x, tid = threadIdx.x;
    for (int i = tid; i < NBK; i += 256) hcnt[i] = 0;
    __syncthreads();
    const v4i* d4 = (const v4i*)(dst + c * EPC);
    for (int i = tid; i < EPC4; i += 256) {
        v4i d = __builtin_nontemporal_load(&d4[i]);
        atomicAdd(&hcnt[d.x >> B_SHIFT], 1);
        atomicAdd(&hcnt[d.y >> B_SHIFT], 1);
        atomicAdd(&hcnt[d.z >> B_SHIFT], 1);
        atomicAdd(&hcnt[d.w >> B_SHIFT], 1);
    }
    __syncthreads();
    for (int b = tid; b < NBK; b += 256) C[c * NBK + b] = hcnt[b];
}

// ---- S1: per-bucket exclusive scan over chunks; PO[c][b], bt[b] ----
__global__ void radix_scan1_kernel(const int* __restrict__ C, int* __restrict__ PO,
                                   int* __restrict__ bt) {
    __shared__ int s[512];
    int b = blockIdx.x, t = threadIdx.x;  // blockDim = 512
    int v = (t < P_CHUNK) ? C[t * NBK + b] : 0;
    s[t] = v;
    __syncthreads();
    for (int off = 1; off < 512; off <<= 1) {
        int x = (t >= off) ? s[t - off] : 0;
        __syncthreads();
        s[t] += x;
        __syncthreads();
    }
    if (t < P_CHUNK) PO[t * NBK + b] = s[t] - v;  // exclusive within bucket
    if (t == 511) bt[b] = s[511];                 // bucket total
}

// ---- S2: exclusive scan of bucket totals -> bb[]; also zeroes pool accum ----
__global__ void radix_scan2_kernel(const int* __restrict__ bt, int* __restrict__ bb,
                                   float* __restrict__ gacc) {
    __shared__ int s[256];
    int t = threadIdx.x;  // blockDim = 256
    int v = (t < NBK) ? bt[t] : 0;
    s[t] = v;
    __syncthreads();
    for (int off = 1; off < 256; off <<= 1) {
        int x = (t >= off) ? s[t - off] : 0;
        __syncthreads();
        s[t] += x;
        __syncthreads();
    }
    if (t < NBK) bb[t] = s[t] - v;
    if (t == 0) bb[NBK] = N_EDGES;
    for (int i = t; i < N_GRAPHS * H_DIM; i += 256) gacc[i] = 0.f;
}

// ---- Pass B: scatter (src,dst) pairs into bucket-major runs ----
__global__ void radix_scatter_kernel(const int* __restrict__ src, const int* __restrict__ dst,
                                     const int* __restrict__ PO, const int* __restrict__ bb,
                                     int2* __restrict__ pairs) {
    __shared__ int cur[NBK];
    int c = blockIdx.x, tid = threadIdx.x;
    for (int b = tid; b < NBK; b += 256) cur[b] = bb[b] + PO[c * NBK + b];
    __syncthreads();
    const v4i* d4 = (const v4i*)(dst + c * EPC);
    const v4i* s4 = (const v4i*)(src + c * EPC);
    for (int i = tid; i < EPC4; i += 256) {
        v4i d = __builtin_nontemporal_load(&d4[i]);
        v4i s = __builtin_nontemporal_load(&s4[i]);
        int2 p;
        int pos;
        pos = atomicAdd(&cur[d.x >> B_SHIFT], 1); p.x = s.x; p.y = d.x; pairs[pos] = p;
        pos = atomicAdd(&cur[d.y >> B_SHIFT], 1); p.x = s.y; p.y = d.y; pairs[pos] = p;
        pos = atomicAdd(&cur[d.z >> B_SHIFT], 1); p.x = s.z; p.y = d.z; pairs[pos] = p;
        pos = atomicAdd(&cur[d.w >> B_SHIFT], 1); p.x = s.w; p.y = d.w; pairs[pos] = p;
    }
}

// ---- Pass C: one block per bucket: count, LDS scan -> row_ptr/dis, scatter csr ----
__global__ void radix_final_kernel(const int2* __restrict__ pairs, const int* __restrict__ bb,
                                   int* __restrict__ row_ptr, float* __restrict__ dis,
                                   int* __restrict__ csr) {
    __shared__ int cnt[NPB];
    __shared__ int s[NPB];
    int b = blockIdx.x, n = threadIdx.x;  // blockDim = NPB = 512
    int node0 = b << B_SHIFT;
    int lo = bb[b], hi = bb[b + 1];
    cnt[n] = 0;
    __syncthreads();
    for (int i = lo + n; i < hi; i += NPB)
        atomicAdd(&cnt[pairs[i].y - node0], 1);
    __syncthreads();
    int deg = cnt[n];
    s[n] = deg;
    __syncthreads();
    for (int off = 1; off < NPB; off <<= 1) {
        int x = (n >= off) ? s[n - off] : 0;
        __syncthreads();
        s[n] += x;
        __syncthreads();
    }
    int start = s[n] - deg;  // exclusive prefix within bucket
    int node = node0 + n;
    if (node < N_NODES) {
        row_ptr[node] = lo + start;
        dis[node] = rsqrtf((float)deg + 1.0f);
    }
    if (b == NBK - 1 && n == 0) row_ptr[N_NODES] = N_EDGES;
    __syncthreads();
    cnt[n] = start;  // reuse as cursor
    __syncthreads();
    for (int i = lo + n; i < hi; i += NPB) {
        int2 p = pairs[i];
        int pos = lo + atomicAdd(&cnt[p.y - node0], 1);
        csr[pos] = p.x;
    }
}

// ---------------- gb = bf16((x @ W1) * dis) : (N x 128) @ (128 x 32) ----------------
__global__ void gemm128_kernel(const float* __restrict__ x, const float* __restrict__ W,
                               const float* __restrict__ dis, ushort_t* __restrict__ out) {
    __shared__ float ws[128 * 32];
    __shared__ float xs[8][128];
    int tid = threadIdx.x;
    const float4* W4 = (const float4*)W;
    float4* ws4 = (float4*)ws;
    for (int i = tid; i < 1024; i += 256) ws4[i] = W4[i];
    int row0 = blockIdx.x * 8;
    const float4* x4 = (const float4*)(x + (size_t)row0 * N_FEAT);
    float4* xs4 = (float4*)xs;
    xs4[tid] = x4[tid];  // 256 float4 = 8 rows x 128
    __syncthreads();
    int r = tid >> 5, j = tid & 31;
    float acc = 0.f;
#pragma unroll
    for (int k = 0; k < 128; k++) acc += xs[r][k] * ws[k * 32 + j];
    out[(row0 + r) * H_DIM + j] = f2bf(acc * dis[row0 + r]);
}

// ---------------- gb = bf16((relu(in) @ W) * dis) : (N x 32) @ (32 x 32) ----------------
template <bool RELU>
__global__ void gemm32_kernel(const float* __restrict__ in, const float* __restrict__ W,
                              const float* __restrict__ dis, ushort_t* __restrict__ out) {
    __shared__ float ws[32 * 32];
    __shared__ float xs[32][32];
    int tid = threadIdx.x;
    const float4* W4 = (const float4*)W;
    float4* ws4 = (float4*)ws;
    for (int i = tid; i < 256; i += 256) ws4[i] = W4[i];
    int row0 = blockIdx.x * 32;
    const float4* in4 = (const float4*)(in + (size_t)row0 * 32);
    float4 v = in4[tid];
    if (RELU) {
        v.x = fmaxf(v.x, 0.f); v.y = fmaxf(v.y, 0.f);
        v.z = fmaxf(v.z, 0.f); v.w = fmaxf(v.w, 0.f);
    }
    ((float4*)xs)[tid] = v;
    __syncthreads();
    int j = tid & 31;
    int r0 = tid >> 5;  // 0..7
    float acc[4] = {0.f, 0.f, 0.f, 0.f};
#pragma unroll
    for (int k = 0; k < 32; k++) {
        float w = ws[k * 32 + j];
#pragma unroll
        for (int m = 0; m < 4; m++) acc[m] += xs[r0 + 8 * m][k] * w;
    }
#pragma unroll
    for (int m = 0; m < 4; m++) {
        int row = row0 + r0 + 8 * m;
        out[row * 32 + j] = f2bf(acc[m] * dis[row]);
    }
}

// ---------------- gather: out[d] = dis[d]*(gb[d] + sum gb[src]) + b ----------------
// gb rows are 64 B (bf16) -> one cache line per random row read (was 2 at fp32).
__global__ void gather_kernel(const int* __restrict__ rp, const int* __restrict__ csr,
                              const ushort_t* __restrict__ gb, const float* __restrict__ dis,
                              const float* __restrict__ b, float* __restrict__ out) {
    int tid = threadIdx.x;
    int row = blockIdx.x * 8 + (tid >> 5);
    int j = tid & 31;
    int lo = rp[row], hi = rp[row + 1];
    float a0 = bf2f(gb[row * 32 + j]);  // self loop: dis*g[d] = dis^2*h[d]
    float a1 = 0.f, a2 = 0.f, a3 = 0.f;
    for (int base = lo; base < hi; base += 32) {
        int cnt = hi - base; if (cnt > 32) cnt = 32;
        int sid = (base + j < hi) ? __builtin_nontemporal_load(&csr[base + j]) : 0;
        int k = 0;
        for (; k + 3 < cnt; k += 4) {
            int s0 = __shfl(sid, k, 32);
            int s1 = __shfl(sid, k + 1, 32);
            int s2 = __shfl(sid, k + 2, 32);
            int s3 = __shfl(sid, k + 3, 32);
            a0 += bf2f(gb[s0 * 32 + j]);
            a1 += bf2f(gb[s1 * 32 + j]);
            a2 += bf2f(gb[s2 * 32 + j]);
            a3 += bf2f(gb[s3 * 32 + j]);
        }
        for (; k < cnt; k++) {
            a0 += bf2f(gb[__shfl(sid, k, 32) * 32 + j]);
        }
    }
    out[row * 32 + j] = dis[row] * (a0 + a1 + a2 + a3) + b[j];
}

// ---------------- pool phase 1: per-256-node partial sums -> gacc atomics ----------------
// batch is sorted: a 256-node window spans <=2 graphs (slot change <=2 per thread).
__global__ void pool_partial_kernel(const float* __restrict__ h, const int* __restrict__ batch,
                                    float* __restrict__ gacc) {
    __shared__ float acc_l[8][32];
    __shared__ int ginfo[2];
    int tid = threadIdx.x;
    int n0 = blockIdx.x * PNPB;
    if (tid < 256) ((float*)acc_l)[tid] = 0.f;
    if (tid == 0) {
        ginfo[0] = batch[n0];
        int last = n0 + PNPB; if (last > N_NODES) last = N_NODES;
        ginfo[1] = batch[last - 1];
    }
    __syncthreads();
    int g_lo = ginfo[0], g_hi = ginfo[1];
    int j = tid & 31;
    float racc = 0.f;
    int cslot = -1;
    for (int rr = tid >> 5; rr < PNPB; rr += 8) {
        int row = n0 + rr;
        if (row >= N_NODES) break;
        int slot = batch[row] - g_lo;
        if (slot != cslot) {
            if (cslot >= 0) {
                if (cslot < 8) atomicAdd(&acc_l[cslot][j], racc);
                else atomicAdd(&gacc[(g_lo + cslot) * H_DIM + j], racc);
            }
            racc = 0.f;
            cslot = slot;
        }
        racc += h[row * H_DIM + j];
    }
    if (cslot >= 0) {
        if (cslot < 8) atomicAdd(&acc_l[cslot][j], racc);
        else atomicAdd(&gacc[(g_lo + cslot) * H_DIM + j], racc);
    }
    __syncthreads();
    int nslots = g_hi - g_lo + 1; if (nslots > 8) nslots = 8;
    int slot = tid >> 5;
    if (slot < nslots && g_lo + slot < N_GRAPHS)
        atomicAdd(&gacc[(g_lo + slot) * H_DIM + j], acc_l[slot][j]);
}

// ---------------- pool phase 2: mean + linear + softmax (one block/graph) ----------------
__global__ void pool_final_kernel(const float* __restrict__ gacc, const int* __restrict__ batch,
                                  const float* __restrict__ Wl, const float* __restrict__ bl,
                                  float* __restrict__ out) {
    __shared__ float pooled[H_DIM];
    __shared__ float logits[N_CLASSES];
    __shared__ int segc;
    int g = blockIdx.x, tid = threadIdx.x;  // blockDim = 64
    if (tid == 0) {
        int lo = 0, hi = N_NODES;
        while (lo < hi) { int m = (lo + hi) >> 1; if (batch[m] < g) lo = m + 1; else hi = m; }
        int a = lo;
        lo = a; hi = N_NODES;
        while (lo < hi) { int m = (lo + hi) >> 1; if (batch[m] < g + 1) lo = m + 1; else hi = m; }
        segc = lo - a;
    }
    __syncthreads();
    if (tid < H_DIM) pooled[tid] = gacc[g * H_DIM + tid] / fmaxf((float)segc, 1.0f);
    __syncthreads();
    if (tid < N_CLASSES) {
        float l = bl[tid];
#pragma unroll
        for (int k = 0; k < H_DIM; k++) l += pooled[k] * Wl[k * N_CLASSES + tid];
        logits[tid] = l;
    }
    __syncthreads();
    if (tid < N_CLASSES) {
        float m = -1e30f;
#pragma unroll
        for (int c = 0; c < N_CLASSES; c++) m = fmaxf(m, logits[c]);
        float s = 0.f;
#pragma unroll
        for (int c = 0; c < N_CLASSES; c++) s += expf(logits[c] - m);
        out[g * N_CLASSES + tid] = expf(logits[tid] - m) / s;
    }
}

extern "C" void kernel_launch(void* const* d_in, const int* in_sizes, int n_in,
                              void* d_out, int out_size, void* d_ws, size_t ws_size,
                              hipStream_t stream) {
    const float* x     = (const float*)d_in[0];
    const int*   ei    = (const int*)d_in[1];
    const int*   batch = (const int*)d_in[2];
    const float* W1 = (const float*)d_in[3];
    const float* b1 = (const float*)d_in[4];
    const float* W2 = (const float*)d_in[5];
    const float* b2 = (const float*)d_in[6];
    const float* W3 = (const float*)d_in[7];
    const float* b3 = (const float*)d_in[8];
    const float* Wl = (const float*)d_in[9];
    const float* bl = (const float*)d_in[10];
    float* out = (float*)d_out;

    const int* src = ei;            // edge_index[0]
    const int* dst = ei + N_EDGES;  // edge_index[1]

    // workspace layout (ints unless noted). pairs aliases gb: pairs is dead
    // after radix_final; gb is first written by gemm128 afterwards (same stream).
    int*     wsi     = (int*)d_ws;
    int*     C       = wsi;                         // P_CHUNK*NBK = 78400
    int*     PO      = C + P_CHUNK * NBK;           // 78400
    int*     bt      = PO + P_CHUNK * NBK;          // NBK
    int*     bb      = bt + NBK;                    // NBK+1
    int*     row_ptr = bb + NBK + 1;                // N_NODES+1
    float*   dis     = (float*)(row_ptr + N_NODES + 1);  // N_NODES
    int*     csr     = (int*)(dis + N_NODES);       // N_EDGES
    int2*    pairs   = (int2*)(csr + N_EDGES);      // N_EDGES int2 (12.8 MB)
    ushort_t* gb     = (ushort_t*)pairs;            // alias: N_NODES*32 bf16 (6.4 MB)
    float*   h_agg   = (float*)(csr + N_EDGES) + 2 * N_EDGES;  // N_NODES*32
    float*   gacc    = h_agg + N_NODES * H_DIM;     // N_GRAPHS*32

    // ---- CSR build: 2-level radix partition (also yields row_ptr, dis) ----
    radix_hist_kernel<<<P_CHUNK, 256, 0, stream>>>(dst, C);
    radix_scan1_kernel<<<NBK, 512, 0, stream>>>(C, PO, bt);
    radix_scan2_kernel<<<1, 256, 0, stream>>>(bt, bb, gacc);
    radix_scatter_kernel<<<P_CHUNK, 256, 0, stream>>>(src, dst, PO, bb, pairs);
    radix_final_kernel<<<NBK, NPB, 0, stream>>>(pairs, bb, row_ptr, dis, csr);

    // ---- layer 1 ----
    gemm128_kernel<<<N_NODES / 8, 256, 0, stream>>>(x, W1, dis, gb);
    gather_kernel<<<N_NODES / 8, 256, 0, stream>>>(row_ptr, csr, gb, dis, b1, h_agg);

    // ---- layer 2 ----
    gemm32_kernel<true><<<N_NODES / 32, 256, 0, stream>>>(h_agg, W2, dis, gb);
    gather_kernel<<<N_NODES / 8, 256, 0, stream>>>(row_ptr, csr, gb, dis, b2, h_agg);

    // ---- layer 3 ----
    gemm32_kernel<true><<<N_NODES / 32, 256, 0, stream>>>(h_agg, W3, dis, gb);
    gather_kernel<<<N_NODES / 8, 256, 0, stream>>>(row_ptr, csr, gb, dis, b3, h_agg);

    // ---- pool: two-phase ----
    pool_partial_kernel<<<PBLK, 256, 0, stream>>>(h_agg, batch, gacc);
    pool_final_kernel<<<N_GRAPHS, 64, 0, stream>>>(gacc, batch, Wl, bl, out);
}